// Round 21
// baseline (654.384 us; speedup 1.0000x reference)
//
#include <hip/hip_runtime.h>
#include <cstdint>

#define NN 100000
#define NE 400000
#define NG 2048
#define H  32
#define ED 16
#define FNPB 16   // nodes per block in k_fused
#define SCB 1024
#define NBL ((NN + SCB - 1) / SCB)   // 98

__device__ __forceinline__ void fma4(float4& a, float s, const float4& w) {
  a.x = fmaf(s, w.x, a.x);
  a.y = fmaf(s, w.y, a.y);
  a.z = fmaf(s, w.z, a.z);
  a.w = fmaf(s, w.w, a.w);
}

__device__ __forceinline__ float sigf(float x) {
  return __builtin_amdgcn_rcpf(1.f + __expf(-x));
}
__device__ __forceinline__ float tanhf_fast(float x) {
  return 1.f - 2.f * __builtin_amdgcn_rcpf(1.f + __expf(2.f * x));
}

// ---- lin0 + pre_nb merged ----
__global__ __launch_bounds__(256) void k_lin0nb(const float* __restrict__ x,
                                                const float* __restrict__ W0,
                                                const float* __restrict__ b0,
                                                const float* __restrict__ Wroot,
                                                const float* __restrict__ bconv,
                                                const float* __restrict__ be,
                                                float* __restrict__ feat,
                                                float* __restrict__ agg,
                                                float* __restrict__ nodeb) {
  __shared__ float w0t[1024];
  __shared__ float wrt[1024];
  __shared__ float sf[256];
  int t = threadIdx.x;
  for (int idx = t; idx < 1024; idx += 256) {
    int o = idx >> 5, i = idx & 31;
    w0t[(i << 5) | o] = W0[idx];
    wrt[(i << 5) | o] = Wroot[idx];
  }
  __syncthreads();
  int id = blockIdx.x * 256 + t;
  int n = id >> 5, o = id & 31;
  int ln = t >> 5;
  const float* xr = x + n * H;
  float acc = b0[o];
#pragma unroll
  for (int i = 0; i < H; ++i) acc = fmaf(xr[i], w0t[(i << 5) | o], acc);
  acc = fmaxf(acc, 0.f);
  feat[id] = acc;
  sf[(ln << 5) | o] = acc;
  __syncthreads();
  float a = bconv[o];
  float nb = 0.f;
#pragma unroll
  for (int i = 0; i < H; ++i) {
    float f = sf[(ln << 5) | i];
    a  = fmaf(f, wrt[(i << 5) | o], a);
    nb = fmaf(f, be[(i << 5) | o], nb);
  }
  agg[id]   = a;
  nodeb[id] = nb;
}

// ---- CSR build ----
__global__ __launch_bounds__(256) void k_hist(const int* __restrict__ ei,
                                              int* __restrict__ deg) {
  int e = blockIdx.x * 256 + threadIdx.x;
  if (e < NE) atomicAdd(&deg[ei[e]], 1);
}

__global__ __launch_bounds__(256) void k_bsum(const int* __restrict__ deg,
                                              int* __restrict__ bsum) {
  __shared__ int red[256];
  int b = blockIdx.x, t = threadIdx.x;
  int base = b * SCB;
  int s = 0;
#pragma unroll
  for (int k = 0; k < 4; ++k) {
    int i = base + k * 256 + t;
    if (i < NN) s += deg[i];
  }
  red[t] = s;
  __syncthreads();
  for (int off = 128; off > 0; off >>= 1) {
    if (t < off) red[t] += red[t + off];
    __syncthreads();
  }
  if (t == 0) bsum[b] = red[0];
}

__global__ __launch_bounds__(128) void k_bscan(const int* __restrict__ bsum,
                                               int* __restrict__ boff,
                                               int* __restrict__ rowptr) {
  __shared__ int sh[128];
  int t = threadIdx.x;
  int v = (t < NBL) ? bsum[t] : 0;
  sh[t] = v;
  __syncthreads();
  for (int off = 1; off < 128; off <<= 1) {
    int u = (t >= off) ? sh[t - off] : 0;
    __syncthreads();
    sh[t] += u;
    __syncthreads();
  }
  if (t < NBL) boff[t] = sh[t] - v;
  if (t == 0) rowptr[NN] = NE;
}

__global__ __launch_bounds__(256) void k_rowptr(const int* __restrict__ deg,
                                                const int* __restrict__ boff,
                                                int* __restrict__ rowptr,
                                                int* __restrict__ nextp) {
  __shared__ int sh[256];
  int b = blockIdx.x, t = threadIdx.x;
  int base = b * SCB + t * 4;
  int d0 = 0, d1 = 0, d2 = 0, d3 = 0;
  if (base + 0 < NN) d0 = deg[base + 0];
  if (base + 1 < NN) d1 = deg[base + 1];
  if (base + 2 < NN) d2 = deg[base + 2];
  if (base + 3 < NN) d3 = deg[base + 3];
  int ts = d0 + d1 + d2 + d3;
  sh[t] = ts;
  __syncthreads();
  for (int off = 1; off < 256; off <<= 1) {
    int u = (t >= off) ? sh[t - off] : 0;
    __syncthreads();
    sh[t] += u;
    __syncthreads();
  }
  int run = boff[b] + sh[t] - ts;
  if (base + 0 < NN) { rowptr[base + 0] = run; nextp[base + 0] = run; run += d0; }
  if (base + 1 < NN) { rowptr[base + 1] = run; nextp[base + 1] = run; run += d1; }
  if (base + 2 < NN) { rowptr[base + 2] = run; nextp[base + 2] = run; run += d2; }
  if (base + 3 < NN) { rowptr[base + 3] = run; nextp[base + 3] = run; run += d3; }
}

__global__ __launch_bounds__(256) void k_scatter(const int* __restrict__ ei,
                                                 const float* __restrict__ ea,
                                                 int* __restrict__ nextp,
                                                 int* __restrict__ src_perm,
                                                 int* __restrict__ dst_perm,
                                                 float* __restrict__ ea_perm) {
  int e = blockIdx.x * 256 + threadIdx.x;
  if (e >= NE) return;
  int src = ei[e], dst = ei[NE + e];
  int p = atomicAdd(&nextp[src], 1);
  src_perm[p] = src;
  dst_perm[p] = dst;
  const float4* s4 = (const float4*)(ea + (size_t)e * ED);
  float4* d4 = (float4*)(ea_perm + (size_t)p * ED);
  d4[0] = s4[0]; d4[1] = s4[1]; d4[2] = s4[2]; d4[3] = s4[3];
}

// ---- weight pre-transpose (once):
// wg6[g][i][o]  (g in {ir,iz,in,hr,hz,hn}), 6144 floats, o-minor
// wrbe[i][64] = [WrootT | be], 2048 floats ----
__global__ __launch_bounds__(256) void k_prep(const float* __restrict__ Wih,
                                              const float* __restrict__ Whh,
                                              const float* __restrict__ Wroot,
                                              const float* __restrict__ be,
                                              float* __restrict__ wg6,
                                              float* __restrict__ wrbe) {
  int idx = blockIdx.x * 256 + threadIdx.x;   // 32 blocks x 256 = 8192 exactly
  if (idx < 6144) {
    int g = idx >> 10, r = idx & 1023;
    int i = r >> 5, o = r & 31;
    wg6[idx] = (g < 3) ? Wih[(g * 32 + o) * 32 + i]
                       : Whh[((g - 3) * 32 + o) * 32 + i];
  } else {
    int r = idx - 6144;
    int i = r >> 6, c = r & 63;
    wrbe[r] = (c < 32) ? Wroot[c * 32 + i] : be[i * 32 + (c - 32)];
  }
}

// ---- fused g+edge (R9 exact) ----
// Phys slot for logical s (o_c=s>>2, q_c=s&3): P(s) = q_c*32 + (o_c ^ (q_c<<1)).
__global__ __launch_bounds__(256) void k_fused(const float* __restrict__ feat,
                                               const float* __restrict__ We,
                                               const float* __restrict__ nodeb_g,
                                               const int* __restrict__ rowptr,
                                               const int* __restrict__ src_perm,
                                               const int* __restrict__ dst_perm,
                                               const float* __restrict__ ea_perm,
                                               float* __restrict__ agg) {
  __shared__ float4 sf4[FNPB * 8];
  __shared__ float  snb[FNPB * 32];
  __shared__ float4 sg4[FNPB * 128];
  int t = threadIdx.x;
  int base = blockIdx.x * FNPB;

  if (t < 128) sf4[t] = ((const float4*)feat)[base * 8 + t];
  snb[t]       = nodeb_g[base * 32 + t];
  snb[t + 256] = nodeb_g[base * 32 + t + 256];
  __syncthreads();

  {
    int cj = t & 127, nh = t >> 7;
    const float4* We4 = (const float4*)We;
    float4 acc[8];
#pragma unroll
    for (int j = 0; j < 8; ++j) acc[j] = make_float4(0.f, 0.f, 0.f, 0.f);
#pragma unroll
    for (int i4 = 0; i4 < 8; ++i4) {
      float4 w0 = We4[(4 * i4 + 0) * 128 + cj];
      float4 w1 = We4[(4 * i4 + 1) * 128 + cj];
      float4 w2 = We4[(4 * i4 + 2) * 128 + cj];
      float4 w3 = We4[(4 * i4 + 3) * 128 + cj];
#pragma unroll
      for (int j = 0; j < 8; ++j) {
        float4 f = sf4[(nh * 8 + j) * 8 + i4];
        fma4(acc[j], f.x, w0);
        fma4(acc[j], f.y, w1);
        fma4(acc[j], f.z, w2);
        fma4(acc[j], f.w, w3);
      }
    }
    int pslot = (cj & 3) * 32 + ((cj >> 2) ^ ((cj & 3) << 1));
#pragma unroll
    for (int j = 0; j < 8; ++j) sg4[(nh * 8 + j) * 128 + pslot] = acc[j];
  }
  __syncthreads();

  int e0 = rowptr[base], e1 = rowptr[base + FNPB];
  int o = t & 31, slot = t >> 5;
  for (int e = e0 + slot; e < e1; e += 8) {
    int src = src_perm[e];
    int dst = dst_perm[e];
    int ln = src - base;
    const float4* e4 = (const float4*)(ea_perm + (size_t)e * ED);
    float acc = snb[ln * 32 + o];
#pragma unroll
    for (int q = 0; q < 4; ++q) {
      float4 gv = sg4[ln * 128 + q * 32 + (o ^ (q << 1))];
      float4 ev = e4[q];
      acc = fmaf(ev.x, gv.x, acc);
      acc = fmaf(ev.y, gv.y, acc);
      acc = fmaf(ev.z, gv.z, acc);
      acc = fmaf(ev.w, gv.w, acc);
    }
    unsafeAtomicAdd(&agg[(size_t)dst * 32 + o], acc);
  }
}

// ---- gru4: flat per-(node,o) mapping, all lanes active, 2 barriers ----
// Weight reads lane-consecutive (conflict-free); m/h reads are broadcasts.
__global__ __launch_bounds__(256) void k_gru4(float* __restrict__ agg,
                                              float* __restrict__ feat,
                                              const float* __restrict__ wg6,
                                              const float* __restrict__ wrbe,
                                              const float* __restrict__ bih,
                                              const float* __restrict__ bhh,
                                              const float* __restrict__ bconv,
                                              float* __restrict__ nodeb,
                                              const int* __restrict__ batch,
                                              float* __restrict__ pooled,
                                              float* __restrict__ cnts,
                                              int do_pre) {
  __shared__ float wl[6144];                   // 24 KB [g][i][o]
  __shared__ float wr[2048];                   // 8 KB [i][64]
  __shared__ float sm[256];                    // m rows (8 nodes)
  __shared__ float sh[256];                    // h rows
  __shared__ float sn[256];                    // h_new rows
  int t = threadIdx.x;
  int id = blockIdx.x * 256 + t;               // grid = 12500
  int ln = t >> 5, o = t & 31;

  for (int idx = t; idx < 6144; idx += 256) wl[idx] = wg6[idx];
  if (do_pre)
    for (int idx = t; idx < 2048; idx += 256) wr[idx] = wrbe[idx];
  float h = feat[id];
  sm[t] = fmaxf(agg[id], 0.f);
  sh[t] = h;
  __syncthreads();

  float gir = 0.f, giz = 0.f, gin = 0.f, ghr = 0.f, ghz = 0.f, ghn = 0.f;
#pragma unroll
  for (int i = 0; i < 32; ++i) {
    float mi = sm[(ln << 5) | i];
    float hi = sh[(ln << 5) | i];
    int w = (i << 5) | o;
    gir = fmaf(mi, wl[w], gir);
    giz = fmaf(mi, wl[1024 + w], giz);
    gin = fmaf(mi, wl[2048 + w], gin);
    ghr = fmaf(hi, wl[3072 + w], ghr);
    ghz = fmaf(hi, wl[4096 + w], ghz);
    ghn = fmaf(hi, wl[5120 + w], ghn);
  }
  float r = sigf((gir + bih[o]) + (ghr + bhh[o]));
  float z = sigf((giz + bih[32 + o]) + (ghz + bhh[32 + o]));
  float n = tanhf_fast((gin + bih[64 + o]) + r * (ghn + bhh[64 + o]));
  float out = (1.f - z) * n + z * h;

  if (do_pre) {
    feat[id] = out;
    sn[t] = out;
    __syncthreads();
    // phase C: agg' = h_new @ WrootT + bconv ; nodeb = h_new @ be-matrix
    float a = bconv[o];
    float nb = 0.f;
#pragma unroll
    for (int i = 0; i < 32; ++i) {
      float f = sn[(ln << 5) | i];
      a  = fmaf(f, wr[(i << 6) + o], a);
      nb = fmaf(f, wr[(i << 6) + 32 + o], nb);
    }
    agg[id]   = a;
    nodeb[id] = nb;
  } else {
    int b = batch[id >> 5];
    unsafeAtomicAdd(&pooled[b * H + o], out);
    if (o == 0) unsafeAtomicAdd(&cnts[b], 1.f);
  }
}

// ---- final head ----
__global__ __launch_bounds__(256) void k_final(const float* __restrict__ pooled,
                                               const float* __restrict__ cnts,
                                               const float* __restrict__ W1,
                                               const float* __restrict__ b1,
                                               float* __restrict__ y) {
  int gph = blockIdx.x * 256 + threadIdx.x;
  if (gph >= NG) return;
  float c = fmaxf(cnts[gph], 1.f);
  float acc = 0.f;
#pragma unroll
  for (int o = 0; o < H; ++o) acc = fmaf(pooled[gph * H + o], W1[o], acc);
  y[gph] = acc / c + b1[0];
}

extern "C" void kernel_launch(void* const* d_in, const int* in_sizes, int n_in,
                              void* d_out, int out_size, void* d_ws, size_t ws_size,
                              hipStream_t stream) {
  const float* x     = (const float*)d_in[0];
  const int*   ei    = (const int*)d_in[1];
  const float* ea    = (const float*)d_in[2];
  const int*   batch = (const int*)d_in[3];
  const float* W0    = (const float*)d_in[4];
  const float* b0    = (const float*)d_in[5];
  const float* We    = (const float*)d_in[6];
  const float* be    = (const float*)d_in[7];
  const float* Wroot = (const float*)d_in[8];
  const float* bconv = (const float*)d_in[9];
  const float* Wih   = (const float*)d_in[10];
  const float* bih   = (const float*)d_in[11];
  const float* Whh   = (const float*)d_in[12];
  const float* bhh   = (const float*)d_in[13];
  const float* W1    = (const float*)d_in[14];
  const float* b1    = (const float*)d_in[15];

  float* ws       = (float*)d_ws;
  float* feat     = ws;                         // 3,200,000
  float* agg      = ws + 3200000;               // 3,200,000
  float* nodeb    = ws + 6400000;               // 3,200,000
  float* pooled   = ws + 9600000;               // 65,536
  float* cnts     = ws + 9665536;               // 2,048
  float* wg6      = ws + 9667584;               // 6,144
  float* wrbe     = ws + 9673728;               // 2,048
  float* ea_perm  = ws + 9675776;               // 6,400,000 (16B aligned)
  int*   ibuf     = (int*)(ws + 16075776);
  int*   deg      = ibuf;                       // 100,000
  int*   rowptr   = ibuf + 100000;              // 100,001
  int*   nextp    = ibuf + 200004;              // 100,000
  int*   src_perm = ibuf + 300004;              // 400,000
  int*   dst_perm = ibuf + 700004;              // 400,000
  int*   bsum     = ibuf + 1100004;             // 98
  int*   boff     = ibuf + 1100104;             // 98

  const int NB_NODE = (NN * H) / 256;           // 12500
  const int NB_E    = (NE + 255) / 256;         // 1563

  hipMemsetAsync(deg, 0, NN * sizeof(int), stream);
  k_hist<<<NB_E, 256, 0, stream>>>(ei, deg);
  k_bsum<<<NBL, 256, 0, stream>>>(deg, bsum);
  k_bscan<<<1, 128, 0, stream>>>(bsum, boff, rowptr);
  k_rowptr<<<NBL, 256, 0, stream>>>(deg, boff, rowptr, nextp);
  k_scatter<<<NB_E, 256, 0, stream>>>(ei, ea, nextp, src_perm, dst_perm, ea_perm);
  k_prep<<<32, 256, 0, stream>>>(Wih, Whh, Wroot, be, wg6, wrbe);

  k_lin0nb<<<NB_NODE, 256, 0, stream>>>(x, W0, b0, Wroot, bconv, be,
                                        feat, agg, nodeb);
  hipMemsetAsync(pooled, 0, (size_t)(NG * H + NG) * 4, stream);
  for (int it = 0; it < 3; ++it) {
    k_fused<<<NN / FNPB, 256, 0, stream>>>(feat, We, nodeb, rowptr, src_perm,
                                           dst_perm, ea_perm, agg);
    k_gru4<<<NB_NODE, 256, 0, stream>>>(agg, feat, wg6, wrbe, bih, bhh, bconv,
                                        nodeb, batch, pooled, cnts,
                                        it < 2 ? 1 : 0);
  }
  k_final<<<(NG + 255) / 256, 256, 0, stream>>>(pooled, cnts, W1, b1, (float*)d_out);
}

// Round 22
// 578.210 us; speedup vs baseline: 1.1317x; 1.1317x over previous
//
#include <hip/hip_runtime.h>
#include <cstdint>

#define NN 100000
#define NE 400000
#define NG 2048
#define H  32
#define ED 16
#define FNPB 16   // nodes per block in k_fused (100000/16 = 6250 blocks)
#define NPB 16    // nodes per block in k_gru3
#define SCB 1024
#define NBL ((NN + SCB - 1) / SCB)   // 98

__device__ __forceinline__ void fma4(float4& a, float s, const float4& w) {
  a.x = fmaf(s, w.x, a.x);
  a.y = fmaf(s, w.y, a.y);
  a.z = fmaf(s, w.z, a.z);
  a.w = fmaf(s, w.w, a.w);
}

// fast sigmoid/tanh: v_exp + v_rcp (1-2 ulp), plenty for 1.56e-4 threshold
__device__ __forceinline__ float sigf(float x) {
  return __builtin_amdgcn_rcpf(1.f + __expf(-x));
}
__device__ __forceinline__ float tanhf_fast(float x) {
  return 1.f - 2.f * __builtin_amdgcn_rcpf(1.f + __expf(2.f * x));
}

// ---------------- lin0: feat = relu(x @ W0^T + b0) ----------------
__global__ __launch_bounds__(256) void k_lin0(const float* __restrict__ x,
                                              const float* __restrict__ W0,
                                              const float* __restrict__ b0,
                                              float* __restrict__ feat) {
  __shared__ float w0t[1024];
  int t = threadIdx.x;
  for (int idx = t; idx < 1024; idx += 256) {
    int o = idx >> 5, i = idx & 31;
    w0t[(i << 5) | o] = W0[idx];
  }
  __syncthreads();
  int id = blockIdx.x * 256 + t;
  int n = id >> 5, o = id & 31;
  const float* xr = x + n * H;
  float acc = b0[o];
#pragma unroll
  for (int i = 0; i < H; ++i) acc = fmaf(xr[i], w0t[(i << 5) | o], acc);
  feat[id] = fmaxf(acc, 0.f);
}

// ---- CSR build ----
__global__ __launch_bounds__(256) void k_hist(const int* __restrict__ ei,
                                              int* __restrict__ deg) {
  int e = blockIdx.x * 256 + threadIdx.x;
  if (e < NE) atomicAdd(&deg[ei[e]], 1);
}

__global__ __launch_bounds__(256) void k_bsum(const int* __restrict__ deg,
                                              int* __restrict__ bsum) {
  __shared__ int red[256];
  int b = blockIdx.x, t = threadIdx.x;
  int base = b * SCB;
  int s = 0;
#pragma unroll
  for (int k = 0; k < 4; ++k) {
    int i = base + k * 256 + t;
    if (i < NN) s += deg[i];
  }
  red[t] = s;
  __syncthreads();
  for (int off = 128; off > 0; off >>= 1) {
    if (t < off) red[t] += red[t + off];
    __syncthreads();
  }
  if (t == 0) bsum[b] = red[0];
}

__global__ __launch_bounds__(128) void k_bscan(const int* __restrict__ bsum,
                                               int* __restrict__ boff,
                                               int* __restrict__ rowptr) {
  __shared__ int sh[128];
  int t = threadIdx.x;
  int v = (t < NBL) ? bsum[t] : 0;
  sh[t] = v;
  __syncthreads();
  for (int off = 1; off < 128; off <<= 1) {
    int u = (t >= off) ? sh[t - off] : 0;
    __syncthreads();
    sh[t] += u;
    __syncthreads();
  }
  if (t < NBL) boff[t] = sh[t] - v;
  if (t == 0) rowptr[NN] = NE;
}

__global__ __launch_bounds__(256) void k_rowptr(const int* __restrict__ deg,
                                                const int* __restrict__ boff,
                                                int* __restrict__ rowptr,
                                                int* __restrict__ nextp) {
  __shared__ int sh[256];
  int b = blockIdx.x, t = threadIdx.x;
  int base = b * SCB + t * 4;
  int d0 = 0, d1 = 0, d2 = 0, d3 = 0;
  if (base + 0 < NN) d0 = deg[base + 0];
  if (base + 1 < NN) d1 = deg[base + 1];
  if (base + 2 < NN) d2 = deg[base + 2];
  if (base + 3 < NN) d3 = deg[base + 3];
  int ts = d0 + d1 + d2 + d3;
  sh[t] = ts;
  __syncthreads();
  for (int off = 1; off < 256; off <<= 1) {
    int u = (t >= off) ? sh[t - off] : 0;
    __syncthreads();
    sh[t] += u;
    __syncthreads();
  }
  int run = boff[b] + sh[t] - ts;
  if (base + 0 < NN) { rowptr[base + 0] = run; nextp[base + 0] = run; run += d0; }
  if (base + 1 < NN) { rowptr[base + 1] = run; nextp[base + 1] = run; run += d1; }
  if (base + 2 < NN) { rowptr[base + 2] = run; nextp[base + 2] = run; run += d2; }
  if (base + 3 < NN) { rowptr[base + 3] = run; nextp[base + 3] = run; run += d3; }
}

__global__ __launch_bounds__(256) void k_scatter(const int* __restrict__ ei,
                                                 const float* __restrict__ ea,
                                                 int* __restrict__ nextp,
                                                 int* __restrict__ src_perm,
                                                 int* __restrict__ dst_perm,
                                                 float* __restrict__ ea_perm) {
  int e = blockIdx.x * 256 + threadIdx.x;
  if (e >= NE) return;
  int src = ei[e], dst = ei[NE + e];
  int p = atomicAdd(&nextp[src], 1);
  src_perm[p] = src;
  dst_perm[p] = dst;
  const float4* s4 = (const float4*)(ea + (size_t)e * ED);
  float4* d4 = (float4*)(ea_perm + (size_t)p * ED);
  d4[0] = s4[0]; d4[1] = s4[1]; d4[2] = s4[2]; d4[3] = s4[3];
}

// ---- weight pre-transpose (once) ----
__global__ __launch_bounds__(256) void k_prep(const float* __restrict__ Wih,
                                              const float* __restrict__ Whh,
                                              const float* __restrict__ Wroot,
                                              const float* __restrict__ be,
                                              float* __restrict__ wcomb,
                                              float* __restrict__ wrbe) {
  int idx = blockIdx.x * 256 + threadIdx.x;
  if (idx < 6144) {
    int i = idx / 192, o = idx % 192;
    wcomb[idx] = (o < 96) ? Wih[o * 32 + i] : Whh[(o - 96) * 32 + i];
  } else if (idx < 8192) {
    int r = idx - 6144;
    int i = r / 64, c = r % 64;
    wrbe[r] = (c < 32) ? Wroot[c * 32 + i] : be[i * 32 + (c - 32)];
  }
}

// ---- one-time agg+nodeb init before iteration 0 ----
__global__ __launch_bounds__(256) void k_pre_nb(const float* __restrict__ feat,
                                                const float* __restrict__ Wroot,
                                                const float* __restrict__ bconv,
                                                const float* __restrict__ be,
                                                float* __restrict__ agg,
                                                float* __restrict__ nodeb) {
  __shared__ float wrt[1024];
  int t = threadIdx.x;
  for (int idx = t; idx < 1024; idx += 256) {
    int o = idx >> 5, i = idx & 31;
    wrt[(i << 5) | o] = Wroot[idx];
  }
  __syncthreads();
  int id = blockIdx.x * 256 + t;
  int n = id >> 5, o = id & 31;
  const float* fr = feat + n * H;
  float a = bconv[o];
  float nb = 0.f;
#pragma unroll
  for (int i = 0; i < H; ++i) {
    float f = fr[i];
    a  = fmaf(f, wrt[(i << 5) | o], a);
    nb = fmaf(f, be[(i << 5) | o], nb);
  }
  agg[id]   = a;
  nodeb[id] = nb;
}

// ---- fused g+edge (R9 exact: best measured): coalesced We reads,
//      global nodeb, XOR-swizzled sg (conflict-free both sides) ----
// Phys slot for logical s (o_c=s>>2, q_c=s&3): P(s) = q_c*32 + (o_c ^ (q_c<<1)).
__global__ __launch_bounds__(256) void k_fused(const float* __restrict__ feat,
                                               const float* __restrict__ We,
                                               const float* __restrict__ nodeb_g,
                                               const int* __restrict__ rowptr,
                                               const int* __restrict__ src_perm,
                                               const int* __restrict__ dst_perm,
                                               const float* __restrict__ ea_perm,
                                               float* __restrict__ agg) {
  __shared__ float4 sf4[FNPB * 8];             // 2 KB
  __shared__ float  snb[FNPB * 32];            // 2 KB
  __shared__ float4 sg4[FNPB * 128];           // 32 KB
  int t = threadIdx.x;
  int base = blockIdx.x * FNPB;

  if (t < 128) sf4[t] = ((const float4*)feat)[base * 8 + t];
  snb[t]       = nodeb_g[base * 32 + t];
  snb[t + 256] = nodeb_g[base * 32 + t + 256];
  __syncthreads();

  // g phase
  {
    int cj = t & 127, nh = t >> 7;
    const float4* We4 = (const float4*)We;     // [32][128], column cj coalesced
    float4 acc[8];
#pragma unroll
    for (int j = 0; j < 8; ++j) acc[j] = make_float4(0.f, 0.f, 0.f, 0.f);
#pragma unroll
    for (int i4 = 0; i4 < 8; ++i4) {
      float4 w0 = We4[(4 * i4 + 0) * 128 + cj];
      float4 w1 = We4[(4 * i4 + 1) * 128 + cj];
      float4 w2 = We4[(4 * i4 + 2) * 128 + cj];
      float4 w3 = We4[(4 * i4 + 3) * 128 + cj];
#pragma unroll
      for (int j = 0; j < 8; ++j) {
        float4 f = sf4[(nh * 8 + j) * 8 + i4];
        fma4(acc[j], f.x, w0);
        fma4(acc[j], f.y, w1);
        fma4(acc[j], f.z, w2);
        fma4(acc[j], f.w, w3);
      }
    }
    int pslot = (cj & 3) * 32 + ((cj >> 2) ^ ((cj & 3) << 1));
#pragma unroll
    for (int j = 0; j < 8; ++j) sg4[(nh * 8 + j) * 128 + pslot] = acc[j];
  }
  __syncthreads();

  // edge phase
  int e0 = rowptr[base], e1 = rowptr[base + FNPB];
  int o = t & 31, slot = t >> 5;
  for (int e = e0 + slot; e < e1; e += 8) {
    int src = src_perm[e];
    int dst = dst_perm[e];
    int ln = src - base;
    const float4* e4 = (const float4*)(ea_perm + (size_t)e * ED);
    float acc = snb[ln * 32 + o];
#pragma unroll
    for (int q = 0; q < 4; ++q) {
      float4 gv = sg4[ln * 128 + q * 32 + (o ^ (q << 1))];
      float4 ev = e4[q];
      acc = fmaf(ev.x, gv.x, acc);
      acc = fmaf(ev.y, gv.y, acc);
      acc = fmaf(ev.z, gv.z, acc);
      acc = fmaf(ev.w, gv.w, acc);
    }
    unsafeAtomicAdd(&agg[(size_t)dst * 32 + o], acc);
  }
}

// ---- gru3 v3 + FAST GATES: phase C writes agg AND nodeb ----
__global__ __launch_bounds__(256) void k_gru3(float* __restrict__ agg,
                                              float* __restrict__ feat,
                                              const float* __restrict__ wcomb,
                                              const float* __restrict__ wrbe,
                                              const float* __restrict__ bih,
                                              const float* __restrict__ bhh,
                                              const float* __restrict__ bconv,
                                              float* __restrict__ nodeb,
                                              int do_pre) {
  __shared__ float4 wlds[1536];                // [32][48] f4 = 24 KB
  __shared__ float4 sm4[NPB * 8];              // m = relu(agg); reused as h_new
  __shared__ float4 sh4[NPB * 8];              // h_old
  __shared__ float4 gl4[NPB * 48];             // 12 KB; head reused as wrbe
  int t = threadIdx.x;
  int base = blockIdx.x * NPB;

  for (int idx = t; idx < 1536; idx += 256) wlds[idx] = ((const float4*)wcomb)[idx];
  if (t < 128) {
    float4 a = ((const float4*)agg)[base * 8 + t];
    a.x = fmaxf(a.x, 0.f); a.y = fmaxf(a.y, 0.f);
    a.z = fmaxf(a.z, 0.f); a.w = fmaxf(a.w, 0.f);
    sm4[t] = a;
    sh4[t] = ((const float4*)feat)[base * 8 + t];
  }
  __syncthreads();

  int wv = t >> 6, lane = t & 63;
  int ln0 = wv * 4;                            // 4 nodes per wave

  // phase A: gi/gh GEMM. lane<24: gi col=lane (input m); 24..47: gh col (input h)
  if (lane < 48) {
    const float4* S4 = (lane < 24) ? sm4 : sh4;
    float4 a0 = make_float4(0.f,0.f,0.f,0.f), a1 = a0, a2 = a0, a3 = a0;
#pragma unroll
    for (int i4 = 0; i4 < 8; ++i4) {
      float4 w0 = wlds[(4 * i4 + 0) * 48 + lane];
      float4 w1 = wlds[(4 * i4 + 1) * 48 + lane];
      float4 w2 = wlds[(4 * i4 + 2) * 48 + lane];
      float4 w3 = wlds[(4 * i4 + 3) * 48 + lane];
      float4 f0 = S4[(ln0 + 0) * 8 + i4];
      float4 f1 = S4[(ln0 + 1) * 8 + i4];
      float4 f2 = S4[(ln0 + 2) * 8 + i4];
      float4 f3 = S4[(ln0 + 3) * 8 + i4];
      fma4(a0, f0.x, w0); fma4(a0, f0.y, w1); fma4(a0, f0.z, w2); fma4(a0, f0.w, w3);
      fma4(a1, f1.x, w0); fma4(a1, f1.y, w1); fma4(a1, f1.z, w2); fma4(a1, f1.w, w3);
      fma4(a2, f2.x, w0); fma4(a2, f2.y, w1); fma4(a2, f2.z, w2); fma4(a2, f2.w, w3);
      fma4(a3, f3.x, w0); fma4(a3, f3.y, w1); fma4(a3, f3.z, w2); fma4(a3, f3.w, w3);
    }
    gl4[(ln0 + 0) * 48 + lane] = a0;
    gl4[(ln0 + 1) * 48 + lane] = a1;
    gl4[(ln0 + 2) * 48 + lane] = a2;
    gl4[(ln0 + 3) * 48 + lane] = a3;
  }
  __syncthreads();

  // phase B: gates elementwise (128 f4-items) with FAST exp/rcp
  if (t < 128) {
    int ln = t >> 3, o4 = t & 7;
    const float4* Bi = (const float4*)bih;
    const float4* Bh = (const float4*)bhh;
    float4 ir = gl4[ln * 48 + o4],       bi0 = Bi[o4];
    float4 iz = gl4[ln * 48 + 8 + o4],   bi1 = Bi[8 + o4];
    float4 in_ = gl4[ln * 48 + 16 + o4], bi2 = Bi[16 + o4];
    float4 hr = gl4[ln * 48 + 24 + o4],  bh0 = Bh[o4];
    float4 hz = gl4[ln * 48 + 32 + o4],  bh1 = Bh[8 + o4];
    float4 hn = gl4[ln * 48 + 40 + o4],  bh2 = Bh[16 + o4];
    float4 h = sh4[ln * 8 + o4];
    float4 out;
#define GATE(c) { \
    float grv = sigf((ir.c + bi0.c) + (hr.c + bh0.c)); \
    float gzv = sigf((iz.c + bi1.c) + (hz.c + bh1.c)); \
    float gnv = tanhf_fast((in_.c + bi2.c) + grv * (hn.c + bh2.c)); \
    out.c = (1.f - gzv) * gnv + gzv * h.c; }
    GATE(x) GATE(y) GATE(z) GATE(w)
#undef GATE
    sm4[ln * 8 + o4] = out;                    // h_new (m consumed in phase A)
    ((float4*)feat)[base * 8 + t] = out;
  }
  __syncthreads();                             // gl4 reads done; sm4 ready

  // phase C: agg_init = h_new @ WrootT + bconv ; nodeb = h_new @ be-matrix
  if (do_pre) {
    gl4[t]       = ((const float4*)wrbe)[t];
    gl4[t + 256] = ((const float4*)wrbe)[t + 256];
    __syncthreads();
    int ln = t >> 4, col = t & 15;             // 256 threads = 16 nodes x 16 cols
    float4 acc = (col < 8) ? ((const float4*)bconv)[col]
                           : make_float4(0.f, 0.f, 0.f, 0.f);
#pragma unroll
    for (int i4 = 0; i4 < 8; ++i4) {
      float4 f  = sm4[ln * 8 + i4];            // h_new
      float4 w0 = gl4[(4 * i4 + 0) * 16 + col];
      float4 w1 = gl4[(4 * i4 + 1) * 16 + col];
      float4 w2 = gl4[(4 * i4 + 2) * 16 + col];
      float4 w3 = gl4[(4 * i4 + 3) * 16 + col];
      fma4(acc, f.x, w0); fma4(acc, f.y, w1); fma4(acc, f.z, w2); fma4(acc, f.w, w3);
    }
    if (col < 8) ((float4*)agg)[(base + ln) * 8 + col] = acc;
    else         ((float4*)nodeb)[(base + ln) * 8 + (col - 8)] = acc;
  }
}

// ---- global mean pool ----
__global__ __launch_bounds__(256) void k_pool(const float* __restrict__ feat,
                                              const int* __restrict__ batch,
                                              float* __restrict__ pooled,
                                              float* __restrict__ cnts) {
  int id = blockIdx.x * 256 + threadIdx.x;
  int n = id >> 5, o = id & 31;
  int b = batch[n];
  unsafeAtomicAdd(&pooled[b * H + o], feat[id]);
  if (o == 0) unsafeAtomicAdd(&cnts[b], 1.f);
}

// ---- final head ----
__global__ __launch_bounds__(256) void k_final(const float* __restrict__ pooled,
                                               const float* __restrict__ cnts,
                                               const float* __restrict__ W1,
                                               const float* __restrict__ b1,
                                               float* __restrict__ y) {
  int gph = blockIdx.x * 256 + threadIdx.x;
  if (gph >= NG) return;
  float c = fmaxf(cnts[gph], 1.f);
  float acc = 0.f;
#pragma unroll
  for (int o = 0; o < H; ++o) acc = fmaf(pooled[gph * H + o], W1[o], acc);
  y[gph] = acc / c + b1[0];
}

extern "C" void kernel_launch(void* const* d_in, const int* in_sizes, int n_in,
                              void* d_out, int out_size, void* d_ws, size_t ws_size,
                              hipStream_t stream) {
  const float* x     = (const float*)d_in[0];
  const int*   ei    = (const int*)d_in[1];
  const float* ea    = (const float*)d_in[2];
  const int*   batch = (const int*)d_in[3];
  const float* W0    = (const float*)d_in[4];
  const float* b0    = (const float*)d_in[5];
  const float* We    = (const float*)d_in[6];
  const float* be    = (const float*)d_in[7];
  const float* Wroot = (const float*)d_in[8];
  const float* bconv = (const float*)d_in[9];
  const float* Wih   = (const float*)d_in[10];
  const float* bih   = (const float*)d_in[11];
  const float* Whh   = (const float*)d_in[12];
  const float* bhh   = (const float*)d_in[13];
  const float* W1    = (const float*)d_in[14];
  const float* b1    = (const float*)d_in[15];

  float* ws       = (float*)d_ws;
  float* feat     = ws;                         // 3,200,000
  float* agg      = ws + 3200000;               // 3,200,000
  float* nodeb    = ws + 6400000;               // 3,200,000
  float* pooled   = ws + 9600000;               // 65,536
  float* cnts     = ws + 9665536;               // 2,048
  float* wcomb    = ws + 9667584;               // 6,144
  float* wrbe     = ws + 9673728;               // 2,048
  float* ea_perm  = ws + 9675776;               // 6,400,000 (16B aligned)
  int*   ibuf     = (int*)(ws + 16075776);
  int*   deg      = ibuf;                       // 100,000
  int*   rowptr   = ibuf + 100000;              // 100,001
  int*   nextp    = ibuf + 200004;              // 100,000
  int*   src_perm = ibuf + 300004;              // 400,000
  int*   dst_perm = ibuf + 700004;              // 400,000
  int*   bsum     = ibuf + 1100004;             // 98
  int*   boff     = ibuf + 1100104;             // 98

  const int NB_NODE = (NN * H) / 256;           // 12500
  const int NB_E    = (NE + 255) / 256;         // 1563

  // one-time CSR build + weight transpose
  hipMemsetAsync(deg, 0, NN * sizeof(int), stream);
  k_hist<<<NB_E, 256, 0, stream>>>(ei, deg);
  k_bsum<<<NBL, 256, 0, stream>>>(deg, bsum);
  k_bscan<<<1, 128, 0, stream>>>(bsum, boff, rowptr);
  k_rowptr<<<NBL, 256, 0, stream>>>(deg, boff, rowptr, nextp);
  k_scatter<<<NB_E, 256, 0, stream>>>(ei, ea, nextp, src_perm, dst_perm, ea_perm);
  k_prep<<<32, 256, 0, stream>>>(Wih, Whh, Wroot, be, wcomb, wrbe);

  k_lin0<<<NB_NODE, 256, 0, stream>>>(x, W0, b0, feat);
  k_pre_nb<<<NB_NODE, 256, 0, stream>>>(feat, Wroot, bconv, be, agg, nodeb);
  for (int it = 0; it < 3; ++it) {
    k_fused<<<NN / FNPB, 256, 0, stream>>>(feat, We, nodeb, rowptr, src_perm,
                                           dst_perm, ea_perm, agg);
    k_gru3<<<NN / NPB, 256, 0, stream>>>(agg, feat, wcomb, wrbe, bih, bhh, bconv,
                                         nodeb, it < 2 ? 1 : 0);
  }
  hipMemsetAsync(pooled, 0, (size_t)(NG * H + NG) * 4, stream);
  k_pool<<<NB_NODE, 256, 0, stream>>>(feat, batch, pooled, cnts);
  k_final<<<(NG + 255) / 256, 256, 0, stream>>>(pooled, cnts, W1, b1, (float*)d_out);
}